// Round 10
// baseline (262.172 us; speedup 1.0000x reference)
//
#include <hip/hip_runtime.h>
#include <math.h>

#define F1 64   // input/hidden features
#define F2 40   // classes
#define NB 1024     // buckets for CSR build (bsh=7 -> 128 nodes/bucket)
#define TILE 4096   // edges per k_bscatter/k_bhist block
#define FCAP 3200   // max staged edges/bucket in k_final (12.8 KB); mean 2046, sigma 45

typedef unsigned int uint;
typedef __attribute__((ext_vector_type(8))) short s8v;   // 8 bf16 (4 VGPR) MFMA A/B frag
typedef __attribute__((ext_vector_type(4))) float f4v;   // 4 f32 MFMA C/D frag

union U8 { s8v s; uint4 q; uint u[4]; };

// ---------- bf16 helpers ----------
__device__ inline unsigned short f2bf(float f) {
    unsigned u = __float_as_uint(f);
    unsigned r = (u + 0x7FFFu + ((u >> 16) & 1u)) >> 16;   // RNE
    return (unsigned short)r;
}
__device__ inline uint packbf(float lo, float hi) {
    return (uint)f2bf(lo) | ((uint)f2bf(hi) << 16);
}
__device__ inline float bf_lo(uint u) { return __uint_as_float(u << 16); }
__device__ inline float bf_hi(uint u) { return __uint_as_float(u & 0xFFFF0000u); }

// split pair (a,b) into packed bf16 hi word + packed bf16 residual word
__device__ inline void split2(float a, float b, uint* hu, uint* lu) {
    unsigned short ha = f2bf(a), hb = f2bf(b);
    *hu = (uint)ha | ((uint)hb << 16);
    float ra = a - __uint_as_float((uint)ha << 16);
    float rb = b - __uint_as_float((uint)hb << 16);
    *lu = packbf(ra, rb);
}

// ---------- pass 1a: bucket histogram ----------
__global__ __launch_bounds__(256) void k_bhist(const int* __restrict__ dst,
                                               int* __restrict__ bcnt, int e, int bsh) {
    __shared__ int h[NB];
    int tid = threadIdx.x;
    for (int i = tid; i < NB; i += 256) h[i] = 0;
    __syncthreads();
    int base = blockIdx.x * TILE;
    int lim = min(base + TILE, e);
    for (int i = base + tid; i < lim; i += 256) atomicAdd(&h[dst[i] >> bsh], 1);
    __syncthreads();
    for (int i = tid; i < NB; i += 256) if (h[i]) atomicAdd(&bcnt[i], h[i]);
}

// ---------- pass 1b: scan of bucket counts ----------
__global__ __launch_bounds__(NB) void k_bscan(const int* __restrict__ bcnt,
                                              int* __restrict__ bptr, int* __restrict__ gcur,
                                              int* __restrict__ row_ptr, int n, int e) {
    __shared__ int sh[NB];
    int t = threadIdx.x;
    sh[t] = bcnt[t];
    __syncthreads();
    for (int off = 1; off < NB; off <<= 1) {
        int v = (t >= off) ? sh[t - off] : 0;
        __syncthreads();
        sh[t] += v;
        __syncthreads();
    }
    int ex = t ? sh[t - 1] : 0;
    bptr[t] = ex;
    gcur[t] = ex;
    if (t == NB - 1) bptr[NB] = sh[NB - 1];
    if (t == 0) row_ptr[n] = e;
}

// ---------- MERGED pass 1c (bucket scatter, 32-bit packed pairs) + GEMM1 ----------
__global__ __launch_bounds__(256) void k_bsg(const int* __restrict__ src,
                                             const int* __restrict__ dst,
                                             int* gcur, uint* __restrict__ pairs,
                                             int e, int bsh, int gt,
                                             const float* __restrict__ x,
                                             const uint4* __restrict__ wf1,
                                             unsigned short* __restrict__ h, int n) {
    __shared__ int lhist[NB];
    __shared__ int lstart[NB];
    __shared__ int delta[NB];
    __shared__ unsigned long long stage[TILE];
    int tid = threadIdx.x;
    if (blockIdx.x < gt) {
        int msk = (1 << bsh) - 1;
        for (int i = tid; i < NB; i += 256) lhist[i] = 0;
        __syncthreads();
        int base = blockIdx.x * TILE;
        int cnt = min(TILE, e - base);
        int sA[16], dA[16], rA[16];
#pragma unroll
        for (int k = 0; k < 16; ++k) {
            int i = base + k * 256 + tid;
            if (i < e) {
                sA[k] = src[i];
                dA[k] = dst[i];
                rA[k] = atomicAdd(&lhist[dA[k] >> bsh], 1);
            }
        }
        __syncthreads();
        if (tid < 64) {
            const int per = NB / 64;
            int v[per];
            int b0 = tid * per, s = 0;
#pragma unroll
            for (int j = 0; j < per; ++j) { v[j] = lhist[b0 + j]; s += v[j]; }
            int sc = s;
            for (int o = 1; o < 64; o <<= 1) { int u = __shfl_up(sc, o); if (tid >= o) sc += u; }
            int ex = sc - s;
#pragma unroll
            for (int j = 0; j < per; ++j) { lstart[b0 + j] = ex; ex += v[j]; }
        }
        __syncthreads();
        for (int i = tid; i < NB; i += 256) {
            int c = lhist[i];
            if (c) delta[i] = atomicAdd(&gcur[i], c) - lstart[i];
        }
        __syncthreads();
#pragma unroll
        for (int k = 0; k < 16; ++k) {
            int i = base + k * 256 + tid;
            if (i < e) {
                int b = dA[k] >> bsh;
                stage[lstart[b] + rA[k]] =
                    ((unsigned long long)(unsigned)sA[k] << 32) | (unsigned)dA[k];
            }
        }
        __syncthreads();
        for (int p = tid; p < cnt; p += 256) {
            unsigned long long pr = stage[p];
            int d = (int)(unsigned)pr;
            int b = d >> bsh;
            pairs[delta[b] + p] = ((uint)(pr >> 32) << bsh) | (uint)(d & msk);
        }
    } else {
        // ---- gemm1 body (no dinv) ----
        int w = tid >> 6, l = tid & 63;
        int node0 = (blockIdx.x - gt) * 64 + w * 16;
        int ar = min(node0 + (l & 15), n - 1);
        const float* ap = x + (size_t)ar * 64 + 8 * (l >> 4);
        float4 a0 = *(const float4*)ap;
        float4 a1 = *(const float4*)(ap + 4);      // ks0: k = 8*(l>>4)+0..7
        float4 a2 = *(const float4*)(ap + 32);
        float4 a3 = *(const float4*)(ap + 36);     // ks1: k = 32+8*(l>>4)+0..7
        U8 ah0, al0, ah1, al1;
        split2(a0.x, a0.y, &ah0.u[0], &al0.u[0]);
        split2(a0.z, a0.w, &ah0.u[1], &al0.u[1]);
        split2(a1.x, a1.y, &ah0.u[2], &al0.u[2]);
        split2(a1.z, a1.w, &ah0.u[3], &al0.u[3]);
        split2(a2.x, a2.y, &ah1.u[0], &al1.u[0]);
        split2(a2.z, a2.w, &ah1.u[1], &al1.u[1]);
        split2(a3.x, a3.y, &ah1.u[2], &al1.u[2]);
        split2(a3.z, a3.w, &ah1.u[3], &al1.u[3]);
        f4v acc[4];
#pragma unroll
        for (int ct = 0; ct < 4; ++ct) acc[ct] = (f4v){0.0f, 0.0f, 0.0f, 0.0f};
#pragma unroll
        for (int ct = 0; ct < 4; ++ct) {
            U8 bh0, bh1, bl0, bl1;
            bh0.q = wf1[(size_t)(0 * 4 + ct) * 64 + l];
            bh1.q = wf1[(size_t)(1 * 4 + ct) * 64 + l];
            bl0.q = wf1[(size_t)(2 * 4 + ct) * 64 + l];
            bl1.q = wf1[(size_t)(3 * 4 + ct) * 64 + l];
            acc[ct] = __builtin_amdgcn_mfma_f32_16x16x32_bf16(ah0.s, bh0.s, acc[ct], 0, 0, 0);
            acc[ct] = __builtin_amdgcn_mfma_f32_16x16x32_bf16(ah1.s, bh1.s, acc[ct], 0, 0, 0);
            acc[ct] = __builtin_amdgcn_mfma_f32_16x16x32_bf16(al0.s, bh0.s, acc[ct], 0, 0, 0);
            acc[ct] = __builtin_amdgcn_mfma_f32_16x16x32_bf16(al1.s, bh1.s, acc[ct], 0, 0, 0);
            acc[ct] = __builtin_amdgcn_mfma_f32_16x16x32_bf16(ah0.s, bl0.s, acc[ct], 0, 0, 0);
            acc[ct] = __builtin_amdgcn_mfma_f32_16x16x32_bf16(ah1.s, bl1.s, acc[ct], 0, 0, 0);
        }
        int r0 = node0 + (l >> 4) * 4;
#pragma unroll
        for (int ct = 0; ct < 4; ++ct)
#pragma unroll
            for (int r = 0; r < 4; ++r)
                if (r0 + r < n)
                    h[(size_t)(r0 + r) * 64 + 16 * ct + (l & 15)] = f2bf(acc[ct][r]);
    }
}

// ---------- pass 2: per-bucket finalize from packed pairs ----------
__global__ __launch_bounds__(256) void k_final(const uint* __restrict__ pairs,
                                               const int* __restrict__ bptr,
                                               int* __restrict__ srcs,
                                               int* __restrict__ row_ptr,
                                               float* __restrict__ dinv,
                                               int n, int bsh) {
    __shared__ int ldeg[128];
    __shared__ int lrow[128];
    __shared__ int lcur[128];
    __shared__ uint stg[FCAP];
    int b = blockIdx.x, tid = threadIdx.x;
    int beg = bptr[b], cnt = bptr[b + 1] - beg;
    int node0 = b << bsh;
    int bnodes = 1 << bsh;   // 128
    int msk = bnodes - 1;
    for (int i = tid; i < bnodes; i += 256) { ldeg[i] = 0; lcur[i] = 0; }
    bool fit = cnt <= FCAP;
    __syncthreads();
    if (fit) {
        for (int p = tid; p < cnt; p += 256) {
            uint pr = pairs[beg + p];
            stg[p] = pr;
            atomicAdd(&ldeg[pr & msk], 1);
        }
    } else {
        for (int p = tid; p < cnt; p += 256)
            atomicAdd(&ldeg[pairs[beg + p] & msk], 1);
    }
    __syncthreads();
    if (tid < 64) {
        int per = bnodes >> 6;   // 2
        int b0 = tid * per, s = 0;
        for (int j = 0; j < per; ++j) s += ldeg[b0 + j];
        int sc = s;
        for (int o = 1; o < 64; o <<= 1) { int u = __shfl_up(sc, o); if (tid >= o) sc += u; }
        int ex = sc - s;
        for (int j = 0; j < per; ++j) { lrow[b0 + j] = ex; ex += ldeg[b0 + j]; }
    }
    __syncthreads();
    for (int i = tid; i < bnodes; i += 256) {
        int node = node0 + i;
        if (node < n) {
            row_ptr[node] = beg + lrow[i];
            dinv[node] = rsqrtf((float)(ldeg[i] + 1));   // +1 self loop
        }
    }
    if (fit) {
        for (int p = tid; p < cnt; p += 256) {
            uint pr = stg[p];
            int dl = pr & msk;
            int r = atomicAdd(&lcur[dl], 1);
            srcs[beg + lrow[dl] + r] = (int)(pr >> bsh);
        }
    } else {
        for (int p = tid; p < cnt; p += 256) {
            uint pr = pairs[beg + p];
            int dl = pr & msk;
            int r = atomicAdd(&lcur[dl], 1);
            srcs[beg + lrow[dl] + r] = (int)(pr >> bsh);
        }
    }
}

// ---------- W prep: pack W1/W2 into MFMA B-fragment order, bf16 hi+lo split ----------
__global__ __launch_bounds__(256) void k_wprep(const float* __restrict__ W1,
                                               const float* __restrict__ W2,
                                               uint4* __restrict__ wf1,
                                               uint4* __restrict__ wf2) {
    int g = blockIdx.x * 256 + threadIdx.x;
    if (g < 512) {                      // W1: 2 ks x 4 ct x 64 lanes
        int ks = g >> 8, ct = (g >> 6) & 3, l = g & 63;
        int c = 16 * ct + (l & 15);
        int kb = 32 * ks + 8 * (l >> 4);
        uint hu[4], lu[4];
#pragma unroll
        for (int i = 0; i < 4; ++i)
            split2(W1[(kb + 2 * i) * 64 + c], W1[(kb + 2 * i + 1) * 64 + c], &hu[i], &lu[i]);
        wf1[(size_t)(ks * 4 + ct) * 64 + l]       = make_uint4(hu[0], hu[1], hu[2], hu[3]);
        wf1[(size_t)((2 + ks) * 4 + ct) * 64 + l] = make_uint4(lu[0], lu[1], lu[2], lu[3]);
    } else if (g < 896) {               // W2: 2 ks x 3 ct x 64 lanes (cols >= 40 zero)
        int v = g - 512;
        int ks = v / 192, rem = v % 192;
        int ct = rem >> 6, l = rem & 63;
        int c = 16 * ct + (l & 15);
        int kb = 32 * ks + 8 * (l >> 4);
        uint hu[4], lu[4];
#pragma unroll
        for (int i = 0; i < 4; ++i) {
            float a = (c < 40) ? W2[(kb + 2 * i) * 40 + c] : 0.0f;
            float b = (c < 40) ? W2[(kb + 2 * i + 1) * 40 + c] : 0.0f;
            split2(a, b, &hu[i], &lu[i]);
        }
        wf2[(size_t)(ks * 3 + ct) * 64 + l]       = make_uint4(hu[0], hu[1], hu[2], hu[3]);
        wf2[(size_t)((2 + ks) * 3 + ct) * 64 + l] = make_uint4(lu[0], lu[1], lu[2], lu[3]);
    }
}

// ---------- FUSED layer-1 gather + layer-2 transform ----------
// Two src-partitioned passes over each node's (register-resident) edge list:
// pass A adds srcs < n/2, pass B srcs >= n/2. Working set per pass = half the
// h table (6.4 MB) -> better per-XCD L2 residency; accumulators stay in regs.
__global__ __launch_bounds__(256) void k_gat(const uint4* __restrict__ h4,
                                             const int* __restrict__ srcs,
                                             const int* __restrict__ row_ptr,
                                             const float* __restrict__ dinv,
                                             const float* __restrict__ b,
                                             const uint4* __restrict__ wf2,
                                             unsigned short* __restrict__ t, int n) {
    __shared__ uint agg[64][36];   // row = 144 B (16 B-aligned), 9.2 KB
    int tid = threadIdx.x;
    int lane = tid & 63;
    int l32 = lane & 31;
    int hw = lane & 32;
    int slot = l32 >> 3, j = l32 & 7;
    int nbase = blockIdx.x * 64;
    int nh = n >> 1;
#pragma unroll 1
    for (int rnd = 0; rnd < 8; ++rnd) {
        int nl = rnd * 8 + (tid >> 5);
        int node = nbase + nl;
        if (node < n) {
            int e0 = row_ptr[node], cnt = row_ptr[node + 1] - e0;
            int idx = (l32 < cnt) ? srcs[e0 + l32] : 0;      // coalesced preload
            float dvp = dinv[idx];                           // L2-resident 400 KB
            float di = dinv[node];
            float a0x=0,a0y=0,a1x=0,a1y=0,a2x=0,a2y=0,a3x=0,a3y=0;
            if (slot == 0) {
                uint4 u = h4[(size_t)node * 8 + j];          // self, scaled by di
                a0x = bf_lo(u.x) * di; a0y = bf_hi(u.x) * di;
                a1x = bf_lo(u.y) * di; a1y = bf_hi(u.y) * di;
                a2x = bf_lo(u.z) * di; a2y = bf_hi(u.z) * di;
                a3x = bf_lo(u.w) * di; a3y = bf_hi(u.w) * di;
            }
            int cl = max(min(cnt, 32) - 1, 0);
#define EDGE(i, CMP) { \
                int e = slot + 4 * (i); \
                int q = hw + min(e, cl); \
                int sv = __shfl(idx, q); \
                float ds = __shfl(dvp, q); \
                if (e < cnt && (CMP)) { \
                    uint4 u = h4[(size_t)sv * 8 + j]; \
                    a0x = fmaf(bf_lo(u.x), ds, a0x);  a0y = fmaf(bf_hi(u.x), ds, a0y); \
                    a1x = fmaf(bf_lo(u.y), ds, a1x);  a1y = fmaf(bf_hi(u.y), ds, a1y); \
                    a2x = fmaf(bf_lo(u.z), ds, a2x);  a2y = fmaf(bf_hi(u.z), ds, a2y); \
                    a3x = fmaf(bf_lo(u.w), ds, a3x);  a3y = fmaf(bf_hi(u.w), ds, a3y); \
                } \
            }
            // pass A: lower half of h table (6.4 MB window)
            EDGE(0, sv < nh) EDGE(1, sv < nh) EDGE(2, sv < nh) EDGE(3, sv < nh)
            EDGE(4, sv < nh) EDGE(5, sv < nh) EDGE(6, sv < nh) EDGE(7, sv < nh)
            // pass B: upper half
            EDGE(0, sv >= nh) EDGE(1, sv >= nh) EDGE(2, sv >= nh) EDGE(3, sv >= nh)
            EDGE(4, sv >= nh) EDGE(5, sv >= nh) EDGE(6, sv >= nh) EDGE(7, sv >= nh)
#undef EDGE
            for (int p = 32 + slot; p < cnt; p += 4) {    // rare tail (deg > 32)
                int s0 = srcs[e0 + p];
                float ds = dinv[s0];
                uint4 u0 = h4[(size_t)s0 * 8 + j];
                a0x = fmaf(bf_lo(u0.x), ds, a0x);  a0y = fmaf(bf_hi(u0.x), ds, a0y);
                a1x = fmaf(bf_lo(u0.y), ds, a1x);  a1y = fmaf(bf_hi(u0.y), ds, a1y);
                a2x = fmaf(bf_lo(u0.z), ds, a2x);  a2y = fmaf(bf_hi(u0.z), ds, a2y);
                a3x = fmaf(bf_lo(u0.w), ds, a3x);  a3y = fmaf(bf_hi(u0.w), ds, a3y);
            }
#define COMB(o) \
            a0x += __shfl_xor(a0x, o); a0y += __shfl_xor(a0y, o); \
            a1x += __shfl_xor(a1x, o); a1y += __shfl_xor(a1y, o); \
            a2x += __shfl_xor(a2x, o); a2y += __shfl_xor(a2y, o); \
            a3x += __shfl_xor(a3x, o); a3y += __shfl_xor(a3y, o);
            COMB(8) COMB(16)
#undef COMB
            if (slot == 0) {
                float4 bl = *(const float4*)&b[8 * j];
                float4 bh = *(const float4*)&b[8 * j + 4];
                float v0 = fmaxf(fmaf(a0x, di, bl.x), 0.0f);
                float v1 = fmaxf(fmaf(a0y, di, bl.y), 0.0f);
                float v2 = fmaxf(fmaf(a1x, di, bl.z), 0.0f);
                float v3 = fmaxf(fmaf(a1y, di, bl.w), 0.0f);
                float v4 = fmaxf(fmaf(a2x, di, bh.x), 0.0f);
                float v5 = fmaxf(fmaf(a2y, di, bh.y), 0.0f);
                float v6 = fmaxf(fmaf(a3x, di, bh.z), 0.0f);
                float v7 = fmaxf(fmaf(a3y, di, bh.w), 0.0f);
                uint4 r;
                r.x = packbf(v0, v1); r.y = packbf(v2, v3);
                r.z = packbf(v4, v5); r.w = packbf(v6, v7);
                *(uint4*)&agg[nl][4 * j] = r;
            }
        }
    }
    __syncthreads();
    // ---- phase 2: trans2 body, A from LDS ----
    int w = tid >> 6, l = tid & 63;
    int node0 = nbase + w * 16;
    int nl = w * 16 + (l & 15);
    U8 a0, a1;
    a0.q = *(const uint4*)&agg[nl][4 * (l >> 4)];        // ks0
    a1.q = *(const uint4*)&agg[nl][16 + 4 * (l >> 4)];   // ks1
    f4v acc[3];
#pragma unroll
    for (int ct = 0; ct < 3; ++ct) acc[ct] = (f4v){0.0f, 0.0f, 0.0f, 0.0f};
#pragma unroll
    for (int ct = 0; ct < 3; ++ct) {
        U8 bh0, bh1, bl0, bl1;
        bh0.q = wf2[(size_t)(0 * 3 + ct) * 64 + l];
        bh1.q = wf2[(size_t)(1 * 3 + ct) * 64 + l];
        bl0.q = wf2[(size_t)(2 * 3 + ct) * 64 + l];
        bl1.q = wf2[(size_t)(3 * 3 + ct) * 64 + l];
        acc[ct] = __builtin_amdgcn_mfma_f32_16x16x32_bf16(a0.s, bh0.s, acc[ct], 0, 0, 0);
        acc[ct] = __builtin_amdgcn_mfma_f32_16x16x32_bf16(a1.s, bh1.s, acc[ct], 0, 0, 0);
        acc[ct] = __builtin_amdgcn_mfma_f32_16x16x32_bf16(a0.s, bl0.s, acc[ct], 0, 0, 0);
        acc[ct] = __builtin_amdgcn_mfma_f32_16x16x32_bf16(a1.s, bl1.s, acc[ct], 0, 0, 0);
    }
    int r0 = node0 + (l >> 4) * 4;
    float dv[4];
#pragma unroll
    for (int r = 0; r < 4; ++r) dv[r] = dinv[min(r0 + r, n - 1)];
#pragma unroll
    for (int ct = 0; ct < 3; ++ct) {
        int col = 16 * ct + (l & 15);
#pragma unroll
        for (int r = 0; r < 4; ++r)
            if (col < 40 && r0 + r < n)
                t[(size_t)(r0 + r) * 40 + col] = f2bf(acc[ct][r] * dv[r]);
    }
}

// ---------- layer-2 gather: src-partitioned two-pass, 3 slots x 10 lanes x uint2 ----------
__global__ __launch_bounds__(256) void k_gather40(const uint2* __restrict__ t2,
                                                  const int* __restrict__ srcs,
                                                  const int* __restrict__ row_ptr,
                                                  const float* __restrict__ dinv,
                                                  const float* __restrict__ b2,
                                                  float* __restrict__ out, int n) {
    int node = (int)(((long long)blockIdx.x * 256 + threadIdx.x) >> 5);
    int lane = threadIdx.x & 63;
    int l32 = lane & 31;
    int hw = lane & 32;
    if (node >= n) return;
    int nh = n >> 1;
    int slot = l32 / 10;             // 0..2 active, 3 idle (l32 30,31)
    int j = l32 - slot * 10;
    int e0 = row_ptr[node];
    int cnt = row_ptr[node + 1] - e0;
    int idx = (l32 < cnt && l32 < 30) ? srcs[e0 + l32] : 0;   // coalesced preload
    float a0=0, a1=0, a2=0, a3=0;
    if (slot == 0) {
        uint2 u = t2[(size_t)node * 10 + j];
        a0 = bf_lo(u.x); a1 = bf_hi(u.x);
        a2 = bf_lo(u.y); a3 = bf_hi(u.y);
    }
    if (slot < 3) {
        int cl = max(min(cnt, 30) - 1, 0);
#define EDGE(i, CMP) { \
            int e = slot + 3 * (i); \
            int sv = __shfl(idx, hw + min(e, cl)); \
            if (e < cnt && (CMP)) { \
                uint2 u = t2[(size_t)sv * 10 + j]; \
                a0 += bf_lo(u.x);  a1 += bf_hi(u.x); \
                a2 += bf_lo(u.y);  a3 += bf_hi(u.y); \
            } \
        }
        // pass A: lower half of t table (4 MB window)
        EDGE(0, sv < nh) EDGE(1, sv < nh) EDGE(2, sv < nh) EDGE(3, sv < nh) EDGE(4, sv < nh)
        EDGE(5, sv < nh) EDGE(6, sv < nh) EDGE(7, sv < nh) EDGE(8, sv < nh) EDGE(9, sv < nh)
        // pass B: upper half
        EDGE(0, sv >= nh) EDGE(1, sv >= nh) EDGE(2, sv >= nh) EDGE(3, sv >= nh) EDGE(4, sv >= nh)
        EDGE(5, sv >= nh) EDGE(6, sv >= nh) EDGE(7, sv >= nh) EDGE(8, sv >= nh) EDGE(9, sv >= nh)
#undef EDGE
        for (int p = 30 + slot; p < cnt; p += 3) {   // rare tail (deg > 30)
            int s0 = srcs[e0 + p];
            uint2 u0 = t2[(size_t)s0 * 10 + j];
            a0 += bf_lo(u0.x);  a1 += bf_hi(u0.x);
            a2 += bf_lo(u0.y);  a3 += bf_hi(u0.y);
        }
    }
    float t0 = a0 + __shfl(a0, lane + 10) + __shfl(a0, lane + 20);
    float t1 = a1 + __shfl(a1, lane + 10) + __shfl(a1, lane + 20);
    float t2s = a2 + __shfl(a2, lane + 10) + __shfl(a2, lane + 20);
    float t3 = a3 + __shfl(a3, lane + 10) + __shfl(a3, lane + 20);
    bool actc = l32 < 10;
    float di = dinv[node];
    float4 bb = actc ? *(const float4*)&b2[4 * l32] : make_float4(0, 0, 0, 0);
    float v0 = fmaf(t0, di, bb.x);
    float v1 = fmaf(t1, di, bb.y);
    float v2 = fmaf(t2s, di, bb.z);
    float v3 = fmaf(t3, di, bb.w);
    float mv = actc ? fmaxf(fmaxf(v0, v1), fmaxf(v2, v3)) : -INFINITY;
    for (int o = 16; o; o >>= 1) mv = fmaxf(mv, __shfl_xor(mv, o));
    float ex = actc ? (expf(v0 - mv) + expf(v1 - mv) + expf(v2 - mv) + expf(v3 - mv)) : 0.0f;
    float s = ex;
    for (int o = 16; o; o >>= 1) s += __shfl_xor(s, o);
    float ls = mv + logf(s);
    if (actc) {
        float4 r = make_float4(v0 - ls, v1 - ls, v2 - ls, v3 - ls);
        *(float4*)&out[(size_t)node * 40 + 4 * l32] = r;
    }
}

extern "C" void kernel_launch(void* const* d_in, const int* in_sizes, int n_in,
                              void* d_out, int out_size, void* d_ws, size_t ws_size,
                              hipStream_t stream) {
    const float* x  = (const float*)d_in[0];
    const int*   ei = (const int*)d_in[1];
    const float* W1 = (const float*)d_in[2];
    const float* b1 = (const float*)d_in[3];
    const float* W2 = (const float*)d_in[4];
    const float* b2 = (const float*)d_in[5];

    const int N = in_sizes[0] / F1;      // 100000
    const int E = in_sizes[1] / 2;       // 1600000
    const int* src = ei;
    const int* dst = ei + E;

    int bsh = 7;
    while ((((N - 1) >> bsh) + 1) > NB) ++bsh;
    const int NBu = ((N - 1) >> bsh) + 1;   // 782

    // workspace layout (16 B-aligned arrays first)
    uint4* h1b     = (uint4*)d_ws;                                // N*8 uint4 (bf16 hs)
    uint2* tb      = (uint2*)(h1b + (size_t)N * 8);               // N*10 uint2 (bf16 ts)
    uint4* wf1     = (uint4*)(tb + (size_t)N * 10);               // 1024 uint4 (16 KB)
    uint4* wf2     = wf1 + 1024;                                  // 768 uint4 (12 KB)
    uint*  pairs   = (uint*)(wf2 + 768);                          // E (packed 24-bit)
    int*   srcs    = (int*)(pairs + E);                           // E
    int*   row_ptr = srcs + E;                                    // N+1
    float* dinv    = (float*)(row_ptr + N + 1);                   // N
    int*   bcnt    = (int*)(dinv + N);                            // NB
    int*   bptr    = bcnt + NB;                                   // NB+1
    int*   gcur    = bptr + NB + 1;                               // NB
    float* outp    = (float*)d_out;                               // N*40

    const int B = 256;
    const int GT = (E + TILE - 1) / TILE;
    const int GM = (N + 63) / 64;   // 64 nodes per block

    // --- W fragment prep (tiny, once) ---
    k_wprep<<<4, B, 0, stream>>>(W1, W2, wf1, wf2);

    // --- CSR build + layer-1 transform (overlapped) ---
    hipMemsetAsync(bcnt, 0, NB * sizeof(int), stream);
    k_bhist<<<GT, B, 0, stream>>>(dst, bcnt, E, bsh);
    k_bscan<<<1, NB, 0, stream>>>(bcnt, bptr, gcur, row_ptr, N, E);
    k_bsg<<<GT + GM, B, 0, stream>>>(src, dst, gcur, pairs, E, bsh, GT,
                                     x, wf1, (unsigned short*)h1b, N);
    k_final<<<NBu, B, 0, stream>>>(pairs, bptr, srcs, row_ptr, dinv, N, bsh);

    // --- fused layer-1 gather + layer-2 transform ---
    k_gat<<<GM, B, 0, stream>>>(h1b, srcs, row_ptr, dinv, b1, wf2,
                                (unsigned short*)tb, N);

    // --- layer 2: gather + bias + log_softmax ---
    k_gather40<<<(N + 7) / 8, B, 0, stream>>>(tb, srcs, row_ptr, dinv, b2, outp, N);
}

// Round 11
// 228.321 us; speedup vs baseline: 1.1483x; 1.1483x over previous
//
#include <hip/hip_runtime.h>
#include <math.h>

#define F1 64   // input/hidden features
#define F2 40   // classes
#define NB 1024     // buckets for CSR build (bsh=7 -> 128 nodes/bucket)
#define TILE 4096   // edges per k_bscatter/k_bhist block
#define FCAP 3200   // max staged edges/bucket in k_final (12.8 KB); mean 2046, sigma 45

typedef unsigned int uint;
typedef __attribute__((ext_vector_type(8))) short s8v;   // 8 bf16 (4 VGPR) MFMA A/B frag
typedef __attribute__((ext_vector_type(4))) float f4v;   // 4 f32 MFMA C/D frag

union U8 { s8v s; uint4 q; uint u[4]; };

// ---------- bf16 helpers ----------
__device__ inline unsigned short f2bf(float f) {
    unsigned u = __float_as_uint(f);
    unsigned r = (u + 0x7FFFu + ((u >> 16) & 1u)) >> 16;   // RNE
    return (unsigned short)r;
}
__device__ inline uint packbf(float lo, float hi) {
    return (uint)f2bf(lo) | ((uint)f2bf(hi) << 16);
}
__device__ inline float bf_lo(uint u) { return __uint_as_float(u << 16); }
__device__ inline float bf_hi(uint u) { return __uint_as_float(u & 0xFFFF0000u); }

// split pair (a,b) into packed bf16 hi word + packed bf16 residual word
__device__ inline void split2(float a, float b, uint* hu, uint* lu) {
    unsigned short ha = f2bf(a), hb = f2bf(b);
    *hu = (uint)ha | ((uint)hb << 16);
    float ra = a - __uint_as_float((uint)ha << 16);
    float rb = b - __uint_as_float((uint)hb << 16);
    *lu = packbf(ra, rb);
}

// ---------- pass 1a: bucket histogram ----------
__global__ __launch_bounds__(256) void k_bhist(const int* __restrict__ dst,
                                               int* __restrict__ bcnt, int e, int bsh) {
    __shared__ int h[NB];
    int tid = threadIdx.x;
    for (int i = tid; i < NB; i += 256) h[i] = 0;
    __syncthreads();
    int base = blockIdx.x * TILE;
    int lim = min(base + TILE, e);
    for (int i = base + tid; i < lim; i += 256) atomicAdd(&h[dst[i] >> bsh], 1);
    __syncthreads();
    for (int i = tid; i < NB; i += 256) if (h[i]) atomicAdd(&bcnt[i], h[i]);
}

// ---------- pass 1b: scan of bucket counts ----------
__global__ __launch_bounds__(NB) void k_bscan(const int* __restrict__ bcnt,
                                              int* __restrict__ bptr, int* __restrict__ gcur,
                                              int* __restrict__ row_ptr, int n, int e) {
    __shared__ int sh[NB];
    int t = threadIdx.x;
    sh[t] = bcnt[t];
    __syncthreads();
    for (int off = 1; off < NB; off <<= 1) {
        int v = (t >= off) ? sh[t - off] : 0;
        __syncthreads();
        sh[t] += v;
        __syncthreads();
    }
    int ex = t ? sh[t - 1] : 0;
    bptr[t] = ex;
    gcur[t] = ex;
    if (t == NB - 1) bptr[NB] = sh[NB - 1];
    if (t == 0) row_ptr[n] = e;
}

// ---------- MERGED pass 1c (bucket scatter, 32-bit packed pairs) + GEMM1 ----------
__global__ __launch_bounds__(256) void k_bsg(const int* __restrict__ src,
                                             const int* __restrict__ dst,
                                             int* gcur, uint* __restrict__ pairs,
                                             int e, int bsh, int gt,
                                             const float* __restrict__ x,
                                             const uint4* __restrict__ wf1,
                                             unsigned short* __restrict__ h, int n) {
    __shared__ int lhist[NB];
    __shared__ int lstart[NB];
    __shared__ int delta[NB];
    __shared__ unsigned long long stage[TILE];
    int tid = threadIdx.x;
    if (blockIdx.x < gt) {
        int msk = (1 << bsh) - 1;
        for (int i = tid; i < NB; i += 256) lhist[i] = 0;
        __syncthreads();
        int base = blockIdx.x * TILE;
        int cnt = min(TILE, e - base);
        int sA[16], dA[16], rA[16];
#pragma unroll
        for (int k = 0; k < 16; ++k) {
            int i = base + k * 256 + tid;
            if (i < e) {
                sA[k] = src[i];
                dA[k] = dst[i];
                rA[k] = atomicAdd(&lhist[dA[k] >> bsh], 1);
            }
        }
        __syncthreads();
        if (tid < 64) {
            const int per = NB / 64;
            int v[per];
            int b0 = tid * per, s = 0;
#pragma unroll
            for (int j = 0; j < per; ++j) { v[j] = lhist[b0 + j]; s += v[j]; }
            int sc = s;
            for (int o = 1; o < 64; o <<= 1) { int u = __shfl_up(sc, o); if (tid >= o) sc += u; }
            int ex = sc - s;
#pragma unroll
            for (int j = 0; j < per; ++j) { lstart[b0 + j] = ex; ex += v[j]; }
        }
        __syncthreads();
        for (int i = tid; i < NB; i += 256) {
            int c = lhist[i];
            if (c) delta[i] = atomicAdd(&gcur[i], c) - lstart[i];
        }
        __syncthreads();
#pragma unroll
        for (int k = 0; k < 16; ++k) {
            int i = base + k * 256 + tid;
            if (i < e) {
                int b = dA[k] >> bsh;
                stage[lstart[b] + rA[k]] =
                    ((unsigned long long)(unsigned)sA[k] << 32) | (unsigned)dA[k];
            }
        }
        __syncthreads();
        for (int p = tid; p < cnt; p += 256) {
            unsigned long long pr = stage[p];
            int d = (int)(unsigned)pr;
            int b = d >> bsh;
            pairs[delta[b] + p] = ((uint)(pr >> 32) << bsh) | (uint)(d & msk);
        }
    } else {
        // ---- gemm1 body (no dinv) ----
        int w = tid >> 6, l = tid & 63;
        int node0 = (blockIdx.x - gt) * 64 + w * 16;
        int ar = min(node0 + (l & 15), n - 1);
        const float* ap = x + (size_t)ar * 64 + 8 * (l >> 4);
        float4 a0 = *(const float4*)ap;
        float4 a1 = *(const float4*)(ap + 4);      // ks0: k = 8*(l>>4)+0..7
        float4 a2 = *(const float4*)(ap + 32);
        float4 a3 = *(const float4*)(ap + 36);     // ks1: k = 32+8*(l>>4)+0..7
        U8 ah0, al0, ah1, al1;
        split2(a0.x, a0.y, &ah0.u[0], &al0.u[0]);
        split2(a0.z, a0.w, &ah0.u[1], &al0.u[1]);
        split2(a1.x, a1.y, &ah0.u[2], &al0.u[2]);
        split2(a1.z, a1.w, &ah0.u[3], &al0.u[3]);
        split2(a2.x, a2.y, &ah1.u[0], &al1.u[0]);
        split2(a2.z, a2.w, &ah1.u[1], &al1.u[1]);
        split2(a3.x, a3.y, &ah1.u[2], &al1.u[2]);
        split2(a3.z, a3.w, &ah1.u[3], &al1.u[3]);
        f4v acc[4];
#pragma unroll
        for (int ct = 0; ct < 4; ++ct) acc[ct] = (f4v){0.0f, 0.0f, 0.0f, 0.0f};
#pragma unroll
        for (int ct = 0; ct < 4; ++ct) {
            U8 bh0, bh1, bl0, bl1;
            bh0.q = wf1[(size_t)(0 * 4 + ct) * 64 + l];
            bh1.q = wf1[(size_t)(1 * 4 + ct) * 64 + l];
            bl0.q = wf1[(size_t)(2 * 4 + ct) * 64 + l];
            bl1.q = wf1[(size_t)(3 * 4 + ct) * 64 + l];
            acc[ct] = __builtin_amdgcn_mfma_f32_16x16x32_bf16(ah0.s, bh0.s, acc[ct], 0, 0, 0);
            acc[ct] = __builtin_amdgcn_mfma_f32_16x16x32_bf16(ah1.s, bh1.s, acc[ct], 0, 0, 0);
            acc[ct] = __builtin_amdgcn_mfma_f32_16x16x32_bf16(al0.s, bh0.s, acc[ct], 0, 0, 0);
            acc[ct] = __builtin_amdgcn_mfma_f32_16x16x32_bf16(al1.s, bh1.s, acc[ct], 0, 0, 0);
            acc[ct] = __builtin_amdgcn_mfma_f32_16x16x32_bf16(ah0.s, bl0.s, acc[ct], 0, 0, 0);
            acc[ct] = __builtin_amdgcn_mfma_f32_16x16x32_bf16(ah1.s, bl1.s, acc[ct], 0, 0, 0);
        }
        int r0 = node0 + (l >> 4) * 4;
#pragma unroll
        for (int ct = 0; ct < 4; ++ct)
#pragma unroll
            for (int r = 0; r < 4; ++r)
                if (r0 + r < n)
                    h[(size_t)(r0 + r) * 64 + 16 * ct + (l & 15)] = f2bf(acc[ct][r]);
    }
}

// ---------- pass 2: per-bucket finalize from packed pairs ----------
__global__ __launch_bounds__(256) void k_final(const uint* __restrict__ pairs,
                                               const int* __restrict__ bptr,
                                               int* __restrict__ srcs,
                                               int* __restrict__ row_ptr,
                                               float* __restrict__ dinv,
                                               int n, int bsh) {
    __shared__ int ldeg[128];
    __shared__ int lrow[128];
    __shared__ int lcur[128];
    __shared__ uint stg[FCAP];
    int b = blockIdx.x, tid = threadIdx.x;
    int beg = bptr[b], cnt = bptr[b + 1] - beg;
    int node0 = b << bsh;
    int bnodes = 1 << bsh;   // 128
    int msk = bnodes - 1;
    for (int i = tid; i < bnodes; i += 256) { ldeg[i] = 0; lcur[i] = 0; }
    bool fit = cnt <= FCAP;
    __syncthreads();
    if (fit) {
        for (int p = tid; p < cnt; p += 256) {
            uint pr = pairs[beg + p];
            stg[p] = pr;
            atomicAdd(&ldeg[pr & msk], 1);
        }
    } else {
        for (int p = tid; p < cnt; p += 256)
            atomicAdd(&ldeg[pairs[beg + p] & msk], 1);
    }
    __syncthreads();
    if (tid < 64) {
        int per = bnodes >> 6;   // 2
        int b0 = tid * per, s = 0;
        for (int j = 0; j < per; ++j) s += ldeg[b0 + j];
        int sc = s;
        for (int o = 1; o < 64; o <<= 1) { int u = __shfl_up(sc, o); if (tid >= o) sc += u; }
        int ex = sc - s;
        for (int j = 0; j < per; ++j) { lrow[b0 + j] = ex; ex += ldeg[b0 + j]; }
    }
    __syncthreads();
    for (int i = tid; i < bnodes; i += 256) {
        int node = node0 + i;
        if (node < n) {
            row_ptr[node] = beg + lrow[i];
            dinv[node] = rsqrtf((float)(ldeg[i] + 1));   // +1 self loop
        }
    }
    if (fit) {
        for (int p = tid; p < cnt; p += 256) {
            uint pr = stg[p];
            int dl = pr & msk;
            int r = atomicAdd(&lcur[dl], 1);
            srcs[beg + lrow[dl] + r] = (int)(pr >> bsh);
        }
    } else {
        for (int p = tid; p < cnt; p += 256) {
            uint pr = pairs[beg + p];
            int dl = pr & msk;
            int r = atomicAdd(&lcur[dl], 1);
            srcs[beg + lrow[dl] + r] = (int)(pr >> bsh);
        }
    }
}

// ---------- W prep: pack W1/W2 into MFMA B-fragment order, bf16 hi+lo split ----------
__global__ __launch_bounds__(256) void k_wprep(const float* __restrict__ W1,
                                               const float* __restrict__ W2,
                                               uint4* __restrict__ wf1,
                                               uint4* __restrict__ wf2) {
    int g = blockIdx.x * 256 + threadIdx.x;
    if (g < 512) {                      // W1: 2 ks x 4 ct x 64 lanes
        int ks = g >> 8, ct = (g >> 6) & 3, l = g & 63;
        int c = 16 * ct + (l & 15);
        int kb = 32 * ks + 8 * (l >> 4);
        uint hu[4], lu[4];
#pragma unroll
        for (int i = 0; i < 4; ++i)
            split2(W1[(kb + 2 * i) * 64 + c], W1[(kb + 2 * i + 1) * 64 + c], &hu[i], &lu[i]);
        wf1[(size_t)(ks * 4 + ct) * 64 + l]       = make_uint4(hu[0], hu[1], hu[2], hu[3]);
        wf1[(size_t)((2 + ks) * 4 + ct) * 64 + l] = make_uint4(lu[0], lu[1], lu[2], lu[3]);
    } else if (g < 896) {               // W2: 2 ks x 3 ct x 64 lanes (cols >= 40 zero)
        int v = g - 512;
        int ks = v / 192, rem = v % 192;
        int ct = rem >> 6, l = rem & 63;
        int c = 16 * ct + (l & 15);
        int kb = 32 * ks + 8 * (l >> 4);
        uint hu[4], lu[4];
#pragma unroll
        for (int i = 0; i < 4; ++i) {
            float a = (c < 40) ? W2[(kb + 2 * i) * 40 + c] : 0.0f;
            float b = (c < 40) ? W2[(kb + 2 * i + 1) * 40 + c] : 0.0f;
            split2(a, b, &hu[i], &lu[i]);
        }
        wf2[(size_t)(ks * 3 + ct) * 64 + l]       = make_uint4(hu[0], hu[1], hu[2], hu[3]);
        wf2[(size_t)((2 + ks) * 3 + ct) * 64 + l] = make_uint4(lu[0], lu[1], lu[2], lu[3]);
    }
}

// ---------- FUSED layer-1 gather + layer-2 transform ----------
// h is UNSCALED; each edge contribution is h[src]*dinv[src] (fma with dinv
// broadcast alongside the index), self contribution h[node]*dinv[node].
__global__ __launch_bounds__(256) void k_gat(const uint4* __restrict__ h4,
                                             const int* __restrict__ srcs,
                                             const int* __restrict__ row_ptr,
                                             const float* __restrict__ dinv,
                                             const float* __restrict__ b,
                                             const uint4* __restrict__ wf2,
                                             unsigned short* __restrict__ t, int n) {
    __shared__ uint agg[64][36];   // row = 144 B (16 B-aligned), 9.2 KB
    int tid = threadIdx.x;
    int lane = tid & 63;
    int l32 = lane & 31;
    int hw = lane & 32;
    int slot = l32 >> 3, j = l32 & 7;
    int nbase = blockIdx.x * 64;
#pragma unroll 1
    for (int rnd = 0; rnd < 8; ++rnd) {
        int nl = rnd * 8 + (tid >> 5);
        int node = nbase + nl;
        if (node < n) {
            int e0 = row_ptr[node], cnt = row_ptr[node + 1] - e0;
            int idx = (l32 < cnt) ? srcs[e0 + l32] : 0;      // coalesced preload
            float dvp = dinv[idx];                           // L2-resident 400 KB
            float di = dinv[node];
            float a0x=0,a0y=0,a1x=0,a1y=0,a2x=0,a2y=0,a3x=0,a3y=0;
            if (slot == 0) {
                uint4 u = h4[(size_t)node * 8 + j];          // self, scaled by di
                a0x = bf_lo(u.x) * di; a0y = bf_hi(u.x) * di;
                a1x = bf_lo(u.y) * di; a1y = bf_hi(u.y) * di;
                a2x = bf_lo(u.z) * di; a2y = bf_hi(u.z) * di;
                a3x = bf_lo(u.w) * di; a3y = bf_hi(u.w) * di;
            }
            int cl = max(min(cnt, 32) - 1, 0);
#pragma unroll
            for (int i = 0; i < 8; ++i) {
                int e = slot + 4 * i;
                int q = hw + min(e, cl);
                int sv = __shfl(idx, q);
                float ds = __shfl(dvp, q);
                uint4 u = h4[(size_t)sv * 8 + j];
                if (e < cnt) {
                    a0x = fmaf(bf_lo(u.x), ds, a0x);  a0y = fmaf(bf_hi(u.x), ds, a0y);
                    a1x = fmaf(bf_lo(u.y), ds, a1x);  a1y = fmaf(bf_hi(u.y), ds, a1y);
                    a2x = fmaf(bf_lo(u.z), ds, a2x);  a2y = fmaf(bf_hi(u.z), ds, a2y);
                    a3x = fmaf(bf_lo(u.w), ds, a3x);  a3y = fmaf(bf_hi(u.w), ds, a3y);
                }
            }
            for (int p = 32 + slot; p < cnt; p += 4) {    // rare tail (deg > 32)
                int s0 = srcs[e0 + p];
                float ds = dinv[s0];
                uint4 u0 = h4[(size_t)s0 * 8 + j];
                a0x = fmaf(bf_lo(u0.x), ds, a0x);  a0y = fmaf(bf_hi(u0.x), ds, a0y);
                a1x = fmaf(bf_lo(u0.y), ds, a1x);  a1y = fmaf(bf_hi(u0.y), ds, a1y);
                a2x = fmaf(bf_lo(u0.z), ds, a2x);  a2y = fmaf(bf_hi(u0.z), ds, a2y);
                a3x = fmaf(bf_lo(u0.w), ds, a3x);  a3y = fmaf(bf_hi(u0.w), ds, a3y);
            }
#define COMB(o) \
            a0x += __shfl_xor(a0x, o); a0y += __shfl_xor(a0y, o); \
            a1x += __shfl_xor(a1x, o); a1y += __shfl_xor(a1y, o); \
            a2x += __shfl_xor(a2x, o); a2y += __shfl_xor(a2y, o); \
            a3x += __shfl_xor(a3x, o); a3y += __shfl_xor(a3y, o);
            COMB(8) COMB(16)
#undef COMB
            if (slot == 0) {
                float4 bl = *(const float4*)&b[8 * j];
                float4 bh = *(const float4*)&b[8 * j + 4];
                float v0 = fmaxf(fmaf(a0x, di, bl.x), 0.0f);
                float v1 = fmaxf(fmaf(a0y, di, bl.y), 0.0f);
                float v2 = fmaxf(fmaf(a1x, di, bl.z), 0.0f);
                float v3 = fmaxf(fmaf(a1y, di, bl.w), 0.0f);
                float v4 = fmaxf(fmaf(a2x, di, bh.x), 0.0f);
                float v5 = fmaxf(fmaf(a2y, di, bh.y), 0.0f);
                float v6 = fmaxf(fmaf(a3x, di, bh.z), 0.0f);
                float v7 = fmaxf(fmaf(a3y, di, bh.w), 0.0f);
                uint4 r;
                r.x = packbf(v0, v1); r.y = packbf(v2, v3);
                r.z = packbf(v4, v5); r.w = packbf(v6, v7);
                *(uint4*)&agg[nl][4 * j] = r;
            }
        }
    }
    __syncthreads();
    // ---- phase 2: trans2 body, A from LDS ----
    int w = tid >> 6, l = tid & 63;
    int node0 = nbase + w * 16;
    int nl = w * 16 + (l & 15);
    U8 a0, a1;
    a0.q = *(const uint4*)&agg[nl][4 * (l >> 4)];        // ks0
    a1.q = *(const uint4*)&agg[nl][16 + 4 * (l >> 4)];   // ks1
    f4v acc[3];
#pragma unroll
    for (int ct = 0; ct < 3; ++ct) acc[ct] = (f4v){0.0f, 0.0f, 0.0f, 0.0f};
#pragma unroll
    for (int ct = 0; ct < 3; ++ct) {
        U8 bh0, bh1, bl0, bl1;
        bh0.q = wf2[(size_t)(0 * 3 + ct) * 64 + l];
        bh1.q = wf2[(size_t)(1 * 3 + ct) * 64 + l];
        bl0.q = wf2[(size_t)(2 * 3 + ct) * 64 + l];
        bl1.q = wf2[(size_t)(3 * 3 + ct) * 64 + l];
        acc[ct] = __builtin_amdgcn_mfma_f32_16x16x32_bf16(a0.s, bh0.s, acc[ct], 0, 0, 0);
        acc[ct] = __builtin_amdgcn_mfma_f32_16x16x32_bf16(a1.s, bh1.s, acc[ct], 0, 0, 0);
        acc[ct] = __builtin_amdgcn_mfma_f32_16x16x32_bf16(a0.s, bl0.s, acc[ct], 0, 0, 0);
        acc[ct] = __builtin_amdgcn_mfma_f32_16x16x32_bf16(a1.s, bl1.s, acc[ct], 0, 0, 0);
    }
    int r0 = node0 + (l >> 4) * 4;
    float dv[4];
#pragma unroll
    for (int r = 0; r < 4; ++r) dv[r] = dinv[min(r0 + r, n - 1)];
#pragma unroll
    for (int ct = 0; ct < 3; ++ct) {
        int col = 16 * ct + (l & 15);
#pragma unroll
        for (int r = 0; r < 4; ++r)
            if (col < 40 && r0 + r < n)
                t[(size_t)(r0 + r) * 40 + col] = f2bf(acc[ct][r] * dv[r]);
    }
}

// ---------- layer-2 gather: one node per HALF-wave, 3 slots x 10 lanes x uint2 ----------
__global__ __launch_bounds__(256) void k_gather40(const uint2* __restrict__ t2,
                                                  const int* __restrict__ srcs,
                                                  const int* __restrict__ row_ptr,
                                                  const float* __restrict__ dinv,
                                                  const float* __restrict__ b2,
                                                  float* __restrict__ out, int n) {
    int node = (int)(((long long)blockIdx.x * 256 + threadIdx.x) >> 5);
    int lane = threadIdx.x & 63;
    int l32 = lane & 31;
    int hw = lane & 32;
    if (node >= n) return;
    int slot = l32 / 10;             // 0..2 active, 3 idle (l32 30,31)
    int j = l32 - slot * 10;
    int e0 = row_ptr[node];
    int cnt = row_ptr[node + 1] - e0;
    int idx = (l32 < cnt && l32 < 30) ? srcs[e0 + l32] : 0;   // coalesced preload
    float a0=0, a1=0, a2=0, a3=0;
    if (slot == 0) {
        uint2 u = t2[(size_t)node * 10 + j];
        a0 = bf_lo(u.x); a1 = bf_hi(u.x);
        a2 = bf_lo(u.y); a3 = bf_hi(u.y);
    }
    if (slot < 3) {
        int cl = max(min(cnt, 30) - 1, 0);
#pragma unroll
        for (int i = 0; i < 10; ++i) {
            int e = slot + 3 * i;
            int sv = __shfl(idx, hw + min(e, cl));
            uint2 u = t2[(size_t)sv * 10 + j];
            if (e < cnt) {
                a0 += bf_lo(u.x);  a1 += bf_hi(u.x);
                a2 += bf_lo(u.y);  a3 += bf_hi(u.y);
            }
        }
        for (int p = 30 + slot; p < cnt; p += 3) {   // rare tail (deg > 30)
            int s0 = srcs[e0 + p];
            uint2 u0 = t2[(size_t)s0 * 10 + j];
            a0 += bf_lo(u0.x);  a1 += bf_hi(u0.x);
            a2 += bf_lo(u0.y);  a3 += bf_hi(u0.y);
        }
    }
    float t0 = a0 + __shfl(a0, lane + 10) + __shfl(a0, lane + 20);
    float t1 = a1 + __shfl(a1, lane + 10) + __shfl(a1, lane + 20);
    float t2s = a2 + __shfl(a2, lane + 10) + __shfl(a2, lane + 20);
    float t3 = a3 + __shfl(a3, lane + 10) + __shfl(a3, lane + 20);
    bool actc = l32 < 10;
    float di = dinv[node];
    float4 bb = actc ? *(const float4*)&b2[4 * l32] : make_float4(0, 0, 0, 0);
    float v0 = fmaf(t0, di, bb.x);
    float v1 = fmaf(t1, di, bb.y);
    float v2 = fmaf(t2s, di, bb.z);
    float v3 = fmaf(t3, di, bb.w);
    float mv = actc ? fmaxf(fmaxf(v0, v1), fmaxf(v2, v3)) : -INFINITY;
    for (int o = 16; o; o >>= 1) mv = fmaxf(mv, __shfl_xor(mv, o));
    float ex = actc ? (expf(v0 - mv) + expf(v1 - mv) + expf(v2 - mv) + expf(v3 - mv)) : 0.0f;
    float s = ex;
    for (int o = 16; o; o >>= 1) s += __shfl_xor(s, o);
    float ls = mv + logf(s);
    if (actc) {
        float4 r = make_float4(v0 - ls, v1 - ls, v2 - ls, v3 - ls);
        *(float4*)&out[(size_t)node * 40 + 4 * l32] = r;
    }
}

extern "C" void kernel_launch(void* const* d_in, const int* in_sizes, int n_in,
                              void* d_out, int out_size, void* d_ws, size_t ws_size,
                              hipStream_t stream) {
    const float* x  = (const float*)d_in[0];
    const int*   ei = (const int*)d_in[1];
    const float* W1 = (const float*)d_in[2];
    const float* b1 = (const float*)d_in[3];
    const float* W2 = (const float*)d_in[4];
    const float* b2 = (const float*)d_in[5];

    const int N = in_sizes[0] / F1;      // 100000
    const int E = in_sizes[1] / 2;       // 1600000
    const int* src = ei;
    const int* dst = ei + E;

    int bsh = 7;
    while ((((N - 1) >> bsh) + 1) > NB) ++bsh;
    const int NBu = ((N - 1) >> bsh) + 1;   // 782

    // workspace layout (16 B-aligned arrays first)
    uint4* h1b     = (uint4*)d_ws;                                // N*8 uint4 (bf16 hs)
    uint2* tb      = (uint2*)(h1b + (size_t)N * 8);               // N*10 uint2 (bf16 ts)
    uint4* wf1     = (uint4*)(tb + (size_t)N * 10);               // 1024 uint4 (16 KB)
    uint4* wf2     = wf1 + 1024;                                  // 768 uint4 (12 KB)
    uint*  pairs   = (uint*)(wf2 + 768);                          // E (packed 24-bit)
    int*   srcs    = (int*)(pairs + E);                           // E
    int*   row_ptr = srcs + E;                                    // N+1
    float* dinv    = (float*)(row_ptr + N + 1);                   // N
    int*   bcnt    = (int*)(dinv + N);                            // NB
    int*   bptr    = bcnt + NB;                                   // NB+1
    int*   gcur    = bptr + NB + 1;                               // NB
    float* outp    = (float*)d_out;                               // N*40

    const int B = 256;
    const int GT = (E + TILE - 1) / TILE;
    const int GM = (N + 63) / 64;   // 64 nodes per block

    // --- W fragment prep (tiny, once) ---
    k_wprep<<<4, B, 0, stream>>>(W1, W2, wf1, wf2);

    // --- CSR build + layer-1 transform (overlapped) ---
    hipMemsetAsync(bcnt, 0, NB * sizeof(int), stream);
    k_bhist<<<GT, B, 0, stream>>>(dst, bcnt, E, bsh);
    k_bscan<<<1, NB, 0, stream>>>(bcnt, bptr, gcur, row_ptr, N, E);
    k_bsg<<<GT + GM, B, 0, stream>>>(src, dst, gcur, pairs, E, bsh, GT,
                                     x, wf1, (unsigned short*)h1b, N);
    k_final<<<NBu, B, 0, stream>>>(pairs, bptr, srcs, row_ptr, dinv, N, bsh);

    // --- fused layer-1 gather + layer-2 transform ---
    k_gat<<<GM, B, 0, stream>>>(h1b, srcs, row_ptr, dinv, b1, wf2,
                                (unsigned short*)tb, N);

    // --- layer 2: gather + bias + log_softmax ---
    k_gather40<<<(N + 7) / 8, B, 0, stream>>>(tb, srcs, row_ptr, dinv, b2, outp, N);
}